// Round 5
// baseline (358.404 us; speedup 1.0000x reference)
//
#include <hip/hip_runtime.h>

#define DIM 256
#define KNN 16
#define SLOPE 0.2f

typedef unsigned short u16;
typedef __attribute__((ext_vector_type(8))) unsigned short u16x8;
typedef __attribute__((ext_vector_type(4))) unsigned short u16x4;
typedef __attribute__((ext_vector_type(8))) short s16x8;
typedef __attribute__((ext_vector_type(4))) float f32x4;

__device__ __forceinline__ float leaky(float x) { return x >= 0.f ? x : SLOPE * x; }
__device__ __forceinline__ u16 f2bu(float f) {
    unsigned int u = __float_as_uint(f);
    u = (u + 0x7FFFu + ((u >> 16) & 1u)) >> 16;
    return (u16)u;
}
__device__ __forceinline__ float bu2f(u16 h) {
    return __uint_as_float(((unsigned int)h) << 16);
}

// ---------------------------------------------------------------------------
// Prep: transpose + convert weights to bf16 [col][k] (k contiguous).
__global__ __launch_bounds__(256) void k_prep(
    const float* __restrict__ w_res, const float* __restrict__ w_init,
    const float* __restrict__ w_fin, u16* __restrict__ wT1, u16* __restrict__ wT3)
{
    const int c = blockIdx.x, t = threadIdx.x;
    if (c < 256)      wT1[c * 256 + t] = f2bu(w_res[t * 256 + c]);
    else if (c < 320) wT1[c * 256 + t] = f2bu(w_init[t * 64 + (c - 256)]);
    else              wT3[(c - 320) * 256 + t] = f2bu(w_fin[t * 256 + (c - 320)]);
}

// ---------------------------------------------------------------------------
// GEMM1 (MFMA): 64 rows/block, 320 cols (0..255 -> resid f32 in d_out,
// 256..319 -> a1 bf16). A full-K in LDS; B fragments read DIRECT from global
// (wT1 is 160 KB, L1/L2-resident) -> no B_s, barrier-free K-loop, 3 blocks/CU.
#define APAD 264  // 256+8 bf16 elems
__global__ __launch_bounds__(256, 3) void k_gemm1(
    const float* __restrict__ in, const u16* __restrict__ wT1,
    const float* __restrict__ b_res, const float* __restrict__ b_init,
    float* __restrict__ resid, u16* __restrict__ a1, int N)
{
    __shared__ u16 A_s[64 * APAD];   // 33792 B
    const int t = threadIdx.x;
    const int base = blockIdx.x * 64;

    // stage A: thread t -> row t>>2, 64-k segment t&3; convert f32->bf16
    {
        const int row = t >> 2, seg = t & 3;
        const int grow = min(base + row, N - 1);
        const float* src = in + (size_t)grow * DIM + seg * 64;
        u16* dst = &A_s[row * APAD + seg * 64];
        #pragma unroll
        for (int j = 0; j < 8; ++j) {
            float4 f0 = *(const float4*)(src + j * 8);
            float4 f1 = *(const float4*)(src + j * 8 + 4);
            u16x8 p;
            p[0] = f2bu(f0.x); p[1] = f2bu(f0.y); p[2] = f2bu(f0.z); p[3] = f2bu(f0.w);
            p[4] = f2bu(f1.x); p[5] = f2bu(f1.y); p[6] = f2bu(f1.z); p[7] = f2bu(f1.w);
            *(u16x8*)(dst + j * 8) = p;
        }
    }
    __syncthreads();

    f32x4 acc[4][5];
    #pragma unroll
    for (int i = 0; i < 4; ++i)
        #pragma unroll
        for (int j = 0; j < 5; ++j)
            acc[i][j] = (f32x4){0.f, 0.f, 0.f, 0.f};

    const int w = t >> 6, lane = t & 63;
    const int llow = lane & 15, lhi = lane >> 4;

    #pragma unroll
    for (int ks = 0; ks < 8; ++ks) {
        s16x8 afrag[4];
        #pragma unroll
        for (int rt = 0; rt < 4; ++rt)
            afrag[rt] = *(const s16x8*)(&A_s[(rt * 16 + llow) * APAD + ks * 32 + lhi * 8]);
        #pragma unroll
        for (int ci = 0; ci < 5; ++ci) {
            const int ct = w * 5 + ci;
            s16x8 bfrag = *(const s16x8*)(wT1 + (size_t)(ct * 16 + llow) * 256 + ks * 32 + lhi * 8);
            #pragma unroll
            for (int rt = 0; rt < 4; ++rt)
                acc[rt][ci] = __builtin_amdgcn_mfma_f32_16x16x32_bf16(
                    afrag[rt], bfrag, acc[rt][ci], 0, 0, 0);
        }
    }

    // epilogue: C map col=lane&15, row=(lane>>4)*4+reg
    #pragma unroll
    for (int ci = 0; ci < 5; ++ci) {
        const int ct = w * 5 + ci;
        const int col = ct * 16 + llow;
        if (col < 256) {
            const float bias = b_res[col];
            #pragma unroll
            for (int rt = 0; rt < 4; ++rt)
                #pragma unroll
                for (int r = 0; r < 4; ++r) {
                    int row = base + rt * 16 + lhi * 4 + r;
                    if (row < N)
                        resid[(size_t)row * DIM + col] = leaky(acc[rt][ci][r] + bias);
                }
        } else {
            const int c2 = col - 256;
            const float bias = b_init[c2];
            #pragma unroll
            for (int rt = 0; rt < 4; ++rt)
                #pragma unroll
                for (int r = 0; r < 4; ++r) {
                    int row = base + rt * 16 + lhi * 4 + r;
                    if (row < N)
                        a1[(size_t)row * 64 + c2] = f2bu(leaky(acc[rt][ci][r] + bias));
                }
        }
    }
}

// ---------------------------------------------------------------------------
// LFA1: 16 points/block. a2[n,0:64] = mean_k leaky(geom@w_g1+b_g1);
// a2[n,64:128] = mean_k a1[idx[n,k],:]. thread = (pt=t>>4, s=t&15), 4 cols each.
__global__ __launch_bounds__(256) void k_lfa1(
    const float* __restrict__ geom, const int* __restrict__ idx,
    const float* __restrict__ w_g1, const float* __restrict__ b_g1,
    const u16* __restrict__ a1, u16* __restrict__ a2, int N)
{
    __shared__ float geom_s[16 * KNN * 4];
    __shared__ int idx_s[16 * KNN];
    const int t = threadIdx.x;
    const int base = blockIdx.x * 16;

    {
        size_t off = (size_t)base * 64 + t * 4;
        size_t mx = (size_t)N * 64 - 4;
        if (off > mx) off = mx;
        *(float4*)&geom_s[t * 4] = *(const float4*)(geom + off);
        int io = base * KNN + t;
        idx_s[t] = idx[min(io, N * KNN - 1)];
    }
    __syncthreads();

    const int pt = t >> 4, s = t & 15;
    const int n = base + pt;

    float wr[4][4], bb[4];
    #pragma unroll
    for (int r = 0; r < 4; ++r)
        #pragma unroll
        for (int j = 0; j < 4; ++j)
            wr[r][j] = w_g1[r * 64 + s * 4 + j];
    #pragma unroll
    for (int j = 0; j < 4; ++j) bb[j] = b_g1[s * 4 + j];

    float accM[4] = {0.f, 0.f, 0.f, 0.f};
    const float4* g4 = (const float4*)&geom_s[pt * 64];
    #pragma unroll
    for (int k = 0; k < KNN; ++k) {
        float4 g = g4[k];
        #pragma unroll
        for (int j = 0; j < 4; ++j)
            accM[j] += leaky(g.x * wr[0][j] + g.y * wr[1][j] + g.z * wr[2][j] + g.w * wr[3][j] + bb[j]);
    }

    float accG[4] = {0.f, 0.f, 0.f, 0.f};
    #pragma unroll
    for (int k = 0; k < KNN; ++k) {
        u16x4 u = *(const u16x4*)(a1 + (size_t)idx_s[pt * KNN + k] * 64 + s * 4);
        #pragma unroll
        for (int j = 0; j < 4; ++j) accG[j] += bu2f(u[j]);
    }

    if (n < N) {
        u16x4 pm, pg;
        #pragma unroll
        for (int j = 0; j < 4; ++j) {
            pm[j] = f2bu(accM[j] * 0.0625f);
            pg[j] = f2bu(accG[j] * 0.0625f);
        }
        *(u16x4*)(a2 + (size_t)n * 128 + s * 4) = pm;
        *(u16x4*)(a2 + (size_t)n * 128 + 64 + s * 4) = pg;
    }
}

// ---------------------------------------------------------------------------
// LFA2 + final GEMM fused: 64 points/block. a3 built in LDS (only LDS user,
// 33.8 KB -> 3 blocks/CU with launch_bounds cap). geom loads are wave-uniform
// (scalar/broadcast, L1); idx loads direct (L1); B fragments direct from
// global wT3 (128 KB, L1/L2-resident). Barrier-free MFMA K-loop. Epilogue:
// leaky(+b_fin) + resid RMW on d_out.
__global__ __launch_bounds__(256, 3) void k_lfa2_fin(
    const float* __restrict__ geom, const int* __restrict__ idx,
    const float* __restrict__ w_g2, const float* __restrict__ b_g2,
    const u16* __restrict__ a2, const u16* __restrict__ wT3,
    const float* __restrict__ b_fin, float* __restrict__ out, int N)
{
    __shared__ u16 a3_s[64 * APAD];  // 33792 B
    const int t = threadIdx.x;
    const int base = blockIdx.x * 64;

    // phase 1: geom MLP -> a3 cols 0..127. thread = (c=t&127, h=t>>7, 32 pts).
    // geom addresses are uniform per wave -> scalar/broadcast loads.
    {
        const int c = t & 127, h = t >> 7;
        const float w0 = w_g2[c], w1 = w_g2[128 + c], w2 = w_g2[256 + c],
                    w3 = w_g2[384 + c], bb = b_g2[c];
        #pragma unroll 4
        for (int p = 0; p < 32; ++p) {
            const int pt = h * 32 + p;
            const int grow = min(base + pt, N - 1);
            const float4* g4 = (const float4*)(geom + (size_t)grow * 64);
            float acc = 0.f;
            #pragma unroll
            for (int k = 0; k < KNN; ++k) {
                float4 g = g4[k];
                acc += leaky(g.x * w0 + g.y * w1 + g.z * w2 + g.w * w3 + bb);
            }
            a3_s[pt * APAD + c] = f2bu(acc * 0.0625f);
        }
    }
    // phase 2: a2 gather -> a3 cols 128..255. thread = (pt=t>>2, q=t&3, 32 cols).
    {
        const int pt = t >> 2, q = t & 3;
        const int irow = min(base + pt, N - 1);
        float acc[32];
        #pragma unroll
        for (int j = 0; j < 32; ++j) acc[j] = 0.f;
        #pragma unroll 4
        for (int k = 0; k < KNN; ++k) {
            const int id = idx[(size_t)irow * KNN + k];
            const u16* row = a2 + (size_t)id * 128 + q * 32;
            #pragma unroll
            for (int v = 0; v < 4; ++v) {
                u16x8 u = *(const u16x8*)(row + v * 8);
                #pragma unroll
                for (int j = 0; j < 8; ++j) acc[v * 8 + j] += bu2f(u[j]);
            }
        }
        #pragma unroll
        for (int v = 0; v < 4; ++v) {
            u16x8 p;
            #pragma unroll
            for (int j = 0; j < 8; ++j) p[j] = f2bu(acc[v * 8 + j] * 0.0625f);
            *(u16x8*)(&a3_s[pt * APAD + 128 + q * 32 + v * 8]) = p;
        }
    }
    __syncthreads();

    f32x4 acc[4][4];
    #pragma unroll
    for (int i = 0; i < 4; ++i)
        #pragma unroll
        for (int j = 0; j < 4; ++j)
            acc[i][j] = (f32x4){0.f, 0.f, 0.f, 0.f};

    const int w = t >> 6, lane = t & 63;
    const int llow = lane & 15, lhi = lane >> 4;

    #pragma unroll
    for (int ks = 0; ks < 8; ++ks) {
        s16x8 afrag[4];
        #pragma unroll
        for (int rt = 0; rt < 4; ++rt)
            afrag[rt] = *(const s16x8*)(&a3_s[(rt * 16 + llow) * APAD + ks * 32 + lhi * 8]);
        #pragma unroll
        for (int ci = 0; ci < 4; ++ci) {
            const int ct = w * 4 + ci;
            s16x8 bfrag = *(const s16x8*)(wT3 + (size_t)(ct * 16 + llow) * 256 + ks * 32 + lhi * 8);
            #pragma unroll
            for (int rt = 0; rt < 4; ++rt)
                acc[rt][ci] = __builtin_amdgcn_mfma_f32_16x16x32_bf16(
                    afrag[rt], bfrag, acc[rt][ci], 0, 0, 0);
        }
    }

    #pragma unroll
    for (int ci = 0; ci < 4; ++ci) {
        const int ct = w * 4 + ci;
        const int col = ct * 16 + llow;
        const float bias = b_fin[col];
        #pragma unroll
        for (int rt = 0; rt < 4; ++rt)
            #pragma unroll
            for (int r = 0; r < 4; ++r) {
                int row = base + rt * 16 + lhi * 4 + r;
                if (row < N) {
                    size_t o = (size_t)row * DIM + col;
                    out[o] = leaky(acc[rt][ci][r] + bias) + out[o];
                }
            }
    }
}

// ---------------------------------------------------------------------------
extern "C" void kernel_launch(void* const* d_in, const int* in_sizes, int n_in,
                              void* d_out, int out_size, void* d_ws, size_t ws_size,
                              hipStream_t stream) {
    const float* in    = (const float*)d_in[0];
    const float* geom  = (const float*)d_in[1];
    const int*   idx   = (const int*)d_in[2];
    const float* w_res = (const float*)d_in[3];
    const float* b_res = (const float*)d_in[4];
    const float* w_init= (const float*)d_in[5];
    const float* b_init= (const float*)d_in[6];
    const float* w_g1  = (const float*)d_in[7];
    const float* b_g1  = (const float*)d_in[8];
    const float* w_g2  = (const float*)d_in[9];
    const float* b_g2  = (const float*)d_in[10];
    const float* w_fin = (const float*)d_in[11];
    const float* b_fin = (const float*)d_in[12];
    float* out = (float*)d_out;

    const int N = in_sizes[0] / DIM;  // 50000

    // ws: a1 N*64 bf16 | a2 N*128 bf16 | wT1 320*256 bf16 | wT3 256*256 bf16
    char* ws = (char*)d_ws;
    u16* a1  = (u16*)ws;
    u16* a2  = (u16*)(ws + (size_t)N * 64 * 2);
    u16* wT1 = (u16*)(ws + (size_t)N * (64 + 128) * 2);
    u16* wT3 = wT1 + 320 * 256;

    k_prep<<<576, 256, 0, stream>>>(w_res, w_init, w_fin, wT1, wT3);
    k_gemm1<<<(N + 63) / 64, 256, 0, stream>>>(in, wT1, b_res, b_init, out, a1, N);
    k_lfa1<<<(N + 15) / 16, 256, 0, stream>>>(geom, idx, w_g1, b_g1, a1, a2, N);
    k_lfa2_fin<<<(N + 63) / 64, 256, 0, stream>>>(geom, idx, w_g2, b_g2, a2, wT3, b_fin, out, N);
}

// Round 6
// 310.348 us; speedup vs baseline: 1.1548x; 1.1548x over previous
//
#include <hip/hip_runtime.h>

#define DIM 256
#define KNN 16
#define SLOPE 0.2f

typedef unsigned short u16;
typedef __attribute__((ext_vector_type(8))) unsigned short u16x8;
typedef __attribute__((ext_vector_type(4))) unsigned short u16x4;
typedef __attribute__((ext_vector_type(8))) short s16x8;
typedef __attribute__((ext_vector_type(4))) float f32x4;

__device__ __forceinline__ float leaky(float x) { return x >= 0.f ? x : SLOPE * x; }
__device__ __forceinline__ u16 f2bu(float f) {
    unsigned int u = __float_as_uint(f);
    u = (u + 0x7FFFu + ((u >> 16) & 1u)) >> 16;
    return (u16)u;
}
__device__ __forceinline__ float bu2f(u16 h) {
    return __uint_as_float(((unsigned int)h) << 16);
}

// ---------------------------------------------------------------------------
// Prep: transpose + convert weights to bf16 [col][k] (k contiguous).
__global__ __launch_bounds__(256) void k_prep(
    const float* __restrict__ w_res, const float* __restrict__ w_init,
    const float* __restrict__ w_fin, u16* __restrict__ wT1, u16* __restrict__ wT3)
{
    const int c = blockIdx.x, t = threadIdx.x;
    if (c < 256)      wT1[c * 256 + t] = f2bu(w_res[t * 256 + c]);
    else if (c < 320) wT1[c * 256 + t] = f2bu(w_init[t * 64 + (c - 256)]);
    else              wT3[(c - 320) * 256 + t] = f2bu(w_fin[t * 256 + (c - 320)]);
}

// ---------------------------------------------------------------------------
// GEMM1 (MFMA, R4 structure): 64 rows/block, 320 cols (0..255 -> resid f32 in
// d_out, 256..319 -> a1 bf16). A full-K in LDS; B staged to LDS per 32-K step.
#define APAD 264  // 256+8 bf16 elems
#define BPAD 40   // 32+8
__global__ __launch_bounds__(256) void k_gemm1(
    const float* __restrict__ in, const u16* __restrict__ wT1,
    const float* __restrict__ b_res, const float* __restrict__ b_init,
    float* __restrict__ resid, u16* __restrict__ a1, int N)
{
    __shared__ u16 A_s[64 * APAD];   // 33792 B
    __shared__ u16 B_s[320 * BPAD];  // 25600 B
    const int t = threadIdx.x;
    const int base = blockIdx.x * 64;

    {
        const int row = t >> 2, seg = t & 3;
        const int grow = min(base + row, N - 1);
        const float* src = in + (size_t)grow * DIM + seg * 64;
        u16* dst = &A_s[row * APAD + seg * 64];
        #pragma unroll
        for (int j = 0; j < 8; ++j) {
            float4 f0 = *(const float4*)(src + j * 8);
            float4 f1 = *(const float4*)(src + j * 8 + 4);
            u16x8 p;
            p[0] = f2bu(f0.x); p[1] = f2bu(f0.y); p[2] = f2bu(f0.z); p[3] = f2bu(f0.w);
            p[4] = f2bu(f1.x); p[5] = f2bu(f1.y); p[6] = f2bu(f1.z); p[7] = f2bu(f1.w);
            *(u16x8*)(dst + j * 8) = p;
        }
    }

    f32x4 acc[4][5];
    #pragma unroll
    for (int i = 0; i < 4; ++i)
        #pragma unroll
        for (int j = 0; j < 5; ++j)
            acc[i][j] = (f32x4){0.f, 0.f, 0.f, 0.f};

    const int w = t >> 6, lane = t & 63;
    const int llow = lane & 15, lhi = lane >> 4;

    for (int ks = 0; ks < 8; ++ks) {
        u16x8 breg[5];
        #pragma unroll
        for (int j = 0; j < 5; ++j) {
            int id = t + 256 * j;
            int col = id >> 2, kg = id & 3;
            breg[j] = *(const u16x8*)(wT1 + col * 256 + ks * 32 + kg * 8);
        }
        __syncthreads();  // prev-step frag reads done (covers A_s on ks=0)
        #pragma unroll
        for (int j = 0; j < 5; ++j) {
            int id = t + 256 * j;
            int col = id >> 2, kg = id & 3;
            *(u16x8*)(&B_s[col * BPAD + kg * 8]) = breg[j];
        }
        __syncthreads();

        s16x8 afrag[4];
        #pragma unroll
        for (int rt = 0; rt < 4; ++rt)
            afrag[rt] = *(const s16x8*)(&A_s[(rt * 16 + llow) * APAD + ks * 32 + lhi * 8]);
        #pragma unroll
        for (int ci = 0; ci < 5; ++ci) {
            const int ct = w * 5 + ci;
            s16x8 bfrag = *(const s16x8*)(&B_s[(ct * 16 + llow) * BPAD + lhi * 8]);
            #pragma unroll
            for (int rt = 0; rt < 4; ++rt)
                acc[rt][ci] = __builtin_amdgcn_mfma_f32_16x16x32_bf16(
                    afrag[rt], bfrag, acc[rt][ci], 0, 0, 0);
        }
    }

    #pragma unroll
    for (int ci = 0; ci < 5; ++ci) {
        const int ct = w * 5 + ci;
        const int col = ct * 16 + llow;
        if (col < 256) {
            const float bias = b_res[col];
            #pragma unroll
            for (int rt = 0; rt < 4; ++rt)
                #pragma unroll
                for (int r = 0; r < 4; ++r) {
                    int row = base + rt * 16 + lhi * 4 + r;
                    if (row < N)
                        resid[(size_t)row * DIM + col] = leaky(acc[rt][ci][r] + bias);
                }
        } else {
            const int c2 = col - 256;
            const float bias = b_init[c2];
            #pragma unroll
            for (int rt = 0; rt < 4; ++rt)
                #pragma unroll
                for (int r = 0; r < 4; ++r) {
                    int row = base + rt * 16 + lhi * 4 + r;
                    if (row < N)
                        a1[(size_t)row * 64 + c2] = f2bu(leaky(acc[rt][ci][r] + bias));
                }
        }
    }
}

// ---------------------------------------------------------------------------
// LFA1: 16 points/block (unchanged from R4).
__global__ __launch_bounds__(256) void k_lfa1(
    const float* __restrict__ geom, const int* __restrict__ idx,
    const float* __restrict__ w_g1, const float* __restrict__ b_g1,
    const u16* __restrict__ a1, u16* __restrict__ a2, int N)
{
    __shared__ float geom_s[16 * KNN * 4];
    __shared__ int idx_s[16 * KNN];
    const int t = threadIdx.x;
    const int base = blockIdx.x * 16;

    {
        size_t off = (size_t)base * 64 + t * 4;
        size_t mx = (size_t)N * 64 - 4;
        if (off > mx) off = mx;
        *(float4*)&geom_s[t * 4] = *(const float4*)(geom + off);
        idx_s[t] = idx[min(base * KNN + t, N * KNN - 1)];
    }
    __syncthreads();

    const int pt = t >> 4, s = t & 15;
    const int n = base + pt;

    float wr[4][4], bb[4];
    #pragma unroll
    for (int r = 0; r < 4; ++r)
        #pragma unroll
        for (int j = 0; j < 4; ++j)
            wr[r][j] = w_g1[r * 64 + s * 4 + j];
    #pragma unroll
    for (int j = 0; j < 4; ++j) bb[j] = b_g1[s * 4 + j];

    float accM[4] = {0.f, 0.f, 0.f, 0.f};
    const float4* g4 = (const float4*)&geom_s[pt * 64];
    #pragma unroll
    for (int k = 0; k < KNN; ++k) {
        float4 g = g4[k];
        #pragma unroll
        for (int j = 0; j < 4; ++j)
            accM[j] += leaky(g.x * wr[0][j] + g.y * wr[1][j] + g.z * wr[2][j] + g.w * wr[3][j] + bb[j]);
    }

    float accG[4] = {0.f, 0.f, 0.f, 0.f};
    u16x4 v[KNN];
    #pragma unroll
    for (int k = 0; k < KNN; ++k)
        v[k] = *(const u16x4*)(a1 + (size_t)idx_s[pt * KNN + k] * 64 + s * 4);
    #pragma unroll
    for (int k = 0; k < KNN; ++k)
        #pragma unroll
        for (int j = 0; j < 4; ++j) accG[j] += bu2f(v[k][j]);

    if (n < N) {
        u16x4 pm, pg;
        #pragma unroll
        for (int j = 0; j < 4; ++j) {
            pm[j] = f2bu(accM[j] * 0.0625f);
            pg[j] = f2bu(accG[j] * 0.0625f);
        }
        *(u16x4*)(a2 + (size_t)n * 128 + s * 4) = pm;
        *(u16x4*)(a2 + (size_t)n * 128 + 64 + s * 4) = pg;
    }
}

// ---------------------------------------------------------------------------
// Gather3: a3h[n,0:128] = mean_k a2[idx[n,k],:]. LDS-light (1 KB), high
// occupancy, 16 fully-unrolled independent 16 B loads per thread.
// thread = (pt = t>>4, s = t&15); 16 threads cover one 256 B a2 row.
__global__ __launch_bounds__(256) void k_gather3(
    const int* __restrict__ idx, const u16* __restrict__ a2,
    u16* __restrict__ a3h, int N)
{
    __shared__ int idx_s[16 * KNN];
    const int t = threadIdx.x;
    const int base = blockIdx.x * 16;
    idx_s[t] = idx[min(base * KNN + t, N * KNN - 1)];
    __syncthreads();

    const int pt = t >> 4, s = t & 15;
    const int n = base + pt;

    u16x8 v[KNN];
    #pragma unroll
    for (int k = 0; k < KNN; ++k)
        v[k] = *(const u16x8*)(a2 + (size_t)idx_s[pt * KNN + k] * 128 + s * 8);

    float acc[8] = {0.f, 0.f, 0.f, 0.f, 0.f, 0.f, 0.f, 0.f};
    #pragma unroll
    for (int k = 0; k < KNN; ++k)
        #pragma unroll
        for (int j = 0; j < 8; ++j) acc[j] += bu2f(v[k][j]);

    u16x8 p;
    #pragma unroll
    for (int j = 0; j < 8; ++j) p[j] = f2bu(acc[j] * 0.0625f);
    if (n < N) *(u16x8*)(a3h + (size_t)n * 128 + s * 8) = p;
}

// ---------------------------------------------------------------------------
// GEMM3: A_s cols 0..127 = geom MLP (computed in-kernel, geom LDS-staged),
// cols 128..255 = copy of a3h. Then MFMA vs wT3 (B_s staged, R4 pattern).
// Epilogue: out = leaky(acc + b_fin) + resid (RMW on d_out).
__global__ __launch_bounds__(256) void k_gemm3(
    const float* __restrict__ geom, const float* __restrict__ w_g2,
    const float* __restrict__ b_g2, const u16* __restrict__ a3h,
    const u16* __restrict__ wT3, const float* __restrict__ b_fin,
    float* __restrict__ out, int N)
{
    __shared__ u16 A_s[64 * APAD];     // 33792 B
    __shared__ u16 B_s[256 * BPAD];    // 20480 B
    __shared__ float geom_s[64 * 64];  // 16384 B
    const int t = threadIdx.x;
    const int base = blockIdx.x * 64;

    // stage geom (coalesced) + copy a3h half into A_s cols 128..255
    {
        size_t mx = (size_t)N * 64 - 4;
        #pragma unroll
        for (int j = 0; j < 4; ++j) {
            size_t off = (size_t)base * 64 + t * 4 + j * 1024;
            if (off > mx) off = mx;
            *(float4*)&geom_s[t * 4 + j * 1024] = *(const float4*)(geom + off);
        }
        const int row = t >> 2, q = t & 3;
        const int grow = min(base + row, N - 1);
        const u16* src = a3h + (size_t)grow * 128 + q * 32;
        u16* dst = &A_s[row * APAD + 128 + q * 32];
        #pragma unroll
        for (int j = 0; j < 4; ++j)
            *(u16x8*)(dst + j * 8) = *(const u16x8*)(src + j * 8);
    }
    __syncthreads();

    // geom MLP -> A_s cols 0..127. thread = (c = t&127, h = t>>7, 32 pts each)
    {
        const int c = t & 127, h = t >> 7;
        const float w0 = w_g2[c], w1 = w_g2[128 + c], w2 = w_g2[256 + c],
                    w3 = w_g2[384 + c], bb = b_g2[c];
        #pragma unroll 4
        for (int p = 0; p < 32; ++p) {
            const int pt = h * 32 + p;
            const float4* g4 = (const float4*)&geom_s[pt * 64];
            float acc = 0.f;
            #pragma unroll
            for (int k = 0; k < KNN; ++k) {
                float4 g = g4[k];
                acc += leaky(g.x * w0 + g.y * w1 + g.z * w2 + g.w * w3 + bb);
            }
            A_s[pt * APAD + c] = f2bu(acc * 0.0625f);
        }
    }

    f32x4 acc[4][4];
    #pragma unroll
    for (int i = 0; i < 4; ++i)
        #pragma unroll
        for (int j = 0; j < 4; ++j)
            acc[i][j] = (f32x4){0.f, 0.f, 0.f, 0.f};

    const int w = t >> 6, lane = t & 63;
    const int llow = lane & 15, lhi = lane >> 4;

    for (int ks = 0; ks < 8; ++ks) {
        u16x8 breg[4];
        #pragma unroll
        for (int kg = 0; kg < 4; ++kg)
            breg[kg] = *(const u16x8*)(wT3 + t * 256 + ks * 32 + kg * 8);
        __syncthreads();  // A_s MLP writes done (ks=0) / prev frag reads done
        #pragma unroll
        for (int kg = 0; kg < 4; ++kg)
            *(u16x8*)(&B_s[t * BPAD + kg * 8]) = breg[kg];
        __syncthreads();

        s16x8 afrag[4];
        #pragma unroll
        for (int rt = 0; rt < 4; ++rt)
            afrag[rt] = *(const s16x8*)(&A_s[(rt * 16 + llow) * APAD + ks * 32 + lhi * 8]);
        #pragma unroll
        for (int ci = 0; ci < 4; ++ci) {
            const int ct = w * 4 + ci;
            s16x8 bfrag = *(const s16x8*)(&B_s[(ct * 16 + llow) * BPAD + lhi * 8]);
            #pragma unroll
            for (int rt = 0; rt < 4; ++rt)
                acc[rt][ci] = __builtin_amdgcn_mfma_f32_16x16x32_bf16(
                    afrag[rt], bfrag, acc[rt][ci], 0, 0, 0);
        }
    }

    #pragma unroll
    for (int ci = 0; ci < 4; ++ci) {
        const int ct = w * 4 + ci;
        const int col = ct * 16 + llow;
        const float bias = b_fin[col];
        #pragma unroll
        for (int rt = 0; rt < 4; ++rt)
            #pragma unroll
            for (int r = 0; r < 4; ++r) {
                int row = base + rt * 16 + lhi * 4 + r;
                if (row < N) {
                    size_t o = (size_t)row * DIM + col;
                    out[o] = leaky(acc[rt][ci][r] + bias) + out[o];
                }
            }
    }
}

// ---------------------------------------------------------------------------
extern "C" void kernel_launch(void* const* d_in, const int* in_sizes, int n_in,
                              void* d_out, int out_size, void* d_ws, size_t ws_size,
                              hipStream_t stream) {
    const float* in    = (const float*)d_in[0];
    const float* geom  = (const float*)d_in[1];
    const int*   idx   = (const int*)d_in[2];
    const float* w_res = (const float*)d_in[3];
    const float* b_res = (const float*)d_in[4];
    const float* w_init= (const float*)d_in[5];
    const float* b_init= (const float*)d_in[6];
    const float* w_g1  = (const float*)d_in[7];
    const float* b_g1  = (const float*)d_in[8];
    const float* w_g2  = (const float*)d_in[9];
    const float* b_g2  = (const float*)d_in[10];
    const float* w_fin = (const float*)d_in[11];
    const float* b_fin = (const float*)d_in[12];
    float* out = (float*)d_out;

    const int N = in_sizes[0] / DIM;  // 50000

    // ws layout (25.9 MB): region0 [N*128 u16] holds a1 (N*64, dead after
    // k_lfa1) then is overwritten by a3h (N*128) | a2 N*128 u16 | wT1 | wT3
    char* ws = (char*)d_ws;
    u16* a1  = (u16*)ws;                          // N*64, lifetime: gemm1->lfa1
    u16* a3h = (u16*)ws;                          // N*128, lifetime: gather3->gemm3
    u16* a2  = (u16*)(ws + (size_t)N * 128 * 2);  // N*128
    u16* wT1 = (u16*)(ws + (size_t)N * 256 * 2);  // 320*256
    u16* wT3 = wT1 + 320 * 256;                   // 256*256

    k_prep<<<576, 256, 0, stream>>>(w_res, w_init, w_fin, wT1, wT3);
    k_gemm1<<<(N + 63) / 64, 256, 0, stream>>>(in, wT1, b_res, b_init, out, a1, N);
    k_lfa1<<<(N + 15) / 16, 256, 0, stream>>>(geom, idx, w_g1, b_g1, a1, a2, N);
    k_gather3<<<(N + 15) / 16, 256, 0, stream>>>(idx, a2, a3h, N);
    k_gemm3<<<(N + 63) / 64, 256, 0, stream>>>(geom, w_g2, b_g2, a3h, wT3, b_fin, out, N);
}

// Round 7
// 296.695 us; speedup vs baseline: 1.2080x; 1.0460x over previous
//
#include <hip/hip_runtime.h>

#define DIM 256
#define KNN 16
#define SLOPE 0.2f

typedef unsigned short u16;
typedef __attribute__((ext_vector_type(8))) unsigned short u16x8;
typedef __attribute__((ext_vector_type(4))) unsigned short u16x4;
typedef __attribute__((ext_vector_type(8))) short s16x8;
typedef __attribute__((ext_vector_type(4))) float f32x4;

__device__ __forceinline__ float leaky(float x) { return x >= 0.f ? x : SLOPE * x; }
__device__ __forceinline__ u16 f2bu(float f) {
    unsigned int u = __float_as_uint(f);
    u = (u + 0x7FFFu + ((u >> 16) & 1u)) >> 16;
    return (u16)u;
}
__device__ __forceinline__ float bu2f(u16 h) {
    return __uint_as_float(((unsigned int)h) << 16);
}

// ---------------------------------------------------------------------------
// Prep: transpose + convert weights to bf16 [col][k] (k contiguous).
__global__ __launch_bounds__(256) void k_prep(
    const float* __restrict__ w_res, const float* __restrict__ w_init,
    const float* __restrict__ w_fin, u16* __restrict__ wT1, u16* __restrict__ wT3)
{
    const int c = blockIdx.x, t = threadIdx.x;
    if (c < 256)      wT1[c * 256 + t] = f2bu(w_res[t * 256 + c]);
    else if (c < 320) wT1[c * 256 + t] = f2bu(w_init[t * 64 + (c - 256)]);
    else              wT3[(c - 320) * 256 + t] = f2bu(w_fin[t * 256 + (c - 320)]);
}

// ---------------------------------------------------------------------------
// GEMM1 (MFMA): 64 rows/block, 320 cols (0..255 -> resid f32 in d_out,
// 256..319 -> a1 bf16). A full-K in LDS; B staged to LDS per 32-K step.
#define APAD 264  // 256+8 bf16 elems
#define BPAD 40   // 32+8
__global__ __launch_bounds__(256) void k_gemm1(
    const float* __restrict__ in, const u16* __restrict__ wT1,
    const float* __restrict__ b_res, const float* __restrict__ b_init,
    float* __restrict__ resid, u16* __restrict__ a1, int N)
{
    __shared__ u16 A_s[64 * APAD];   // 33792 B
    __shared__ u16 B_s[320 * BPAD];  // 25600 B
    const int t = threadIdx.x;
    const int base = blockIdx.x * 64;

    {
        const int row = t >> 2, seg = t & 3;
        const int grow = min(base + row, N - 1);
        const float* src = in + (size_t)grow * DIM + seg * 64;
        u16* dst = &A_s[row * APAD + seg * 64];
        #pragma unroll
        for (int j = 0; j < 8; ++j) {
            float4 f0 = *(const float4*)(src + j * 8);
            float4 f1 = *(const float4*)(src + j * 8 + 4);
            u16x8 p;
            p[0] = f2bu(f0.x); p[1] = f2bu(f0.y); p[2] = f2bu(f0.z); p[3] = f2bu(f0.w);
            p[4] = f2bu(f1.x); p[5] = f2bu(f1.y); p[6] = f2bu(f1.z); p[7] = f2bu(f1.w);
            *(u16x8*)(dst + j * 8) = p;
        }
    }

    f32x4 acc[4][5];
    #pragma unroll
    for (int i = 0; i < 4; ++i)
        #pragma unroll
        for (int j = 0; j < 5; ++j)
            acc[i][j] = (f32x4){0.f, 0.f, 0.f, 0.f};

    const int w = t >> 6, lane = t & 63;
    const int llow = lane & 15, lhi = lane >> 4;

    for (int ks = 0; ks < 8; ++ks) {
        u16x8 breg[5];
        #pragma unroll
        for (int j = 0; j < 5; ++j) {
            int id = t + 256 * j;
            int col = id >> 2, kg = id & 3;
            breg[j] = *(const u16x8*)(wT1 + col * 256 + ks * 32 + kg * 8);
        }
        __syncthreads();  // prev-step frag reads done (covers A_s on ks=0)
        #pragma unroll
        for (int j = 0; j < 5; ++j) {
            int id = t + 256 * j;
            int col = id >> 2, kg = id & 3;
            *(u16x8*)(&B_s[col * BPAD + kg * 8]) = breg[j];
        }
        __syncthreads();

        s16x8 afrag[4];
        #pragma unroll
        for (int rt = 0; rt < 4; ++rt)
            afrag[rt] = *(const s16x8*)(&A_s[(rt * 16 + llow) * APAD + ks * 32 + lhi * 8]);
        #pragma unroll
        for (int ci = 0; ci < 5; ++ci) {
            const int ct = w * 5 + ci;
            s16x8 bfrag = *(const s16x8*)(&B_s[(ct * 16 + llow) * BPAD + lhi * 8]);
            #pragma unroll
            for (int rt = 0; rt < 4; ++rt)
                acc[rt][ci] = __builtin_amdgcn_mfma_f32_16x16x32_bf16(
                    afrag[rt], bfrag, acc[rt][ci], 0, 0, 0);
        }
    }

    #pragma unroll
    for (int ci = 0; ci < 5; ++ci) {
        const int ct = w * 5 + ci;
        const int col = ct * 16 + llow;
        if (col < 256) {
            const float bias = b_res[col];
            #pragma unroll
            for (int rt = 0; rt < 4; ++rt)
                #pragma unroll
                for (int r = 0; r < 4; ++r) {
                    int row = base + rt * 16 + lhi * 4 + r;
                    if (row < N)
                        resid[(size_t)row * DIM + col] = leaky(acc[rt][ci][r] + bias);
                }
        } else {
            const int c2 = col - 256;
            const float bias = b_init[c2];
            #pragma unroll
            for (int rt = 0; rt < 4; ++rt)
                #pragma unroll
                for (int r = 0; r < 4; ++r) {
                    int row = base + rt * 16 + lhi * 4 + r;
                    if (row < N)
                        a1[(size_t)row * 64 + c2] = f2bu(leaky(acc[rt][ci][r] + bias));
                }
        }
    }
}

// ---------------------------------------------------------------------------
// LFA1: 16 points/block.
__global__ __launch_bounds__(256) void k_lfa1(
    const float* __restrict__ geom, const int* __restrict__ idx,
    const float* __restrict__ w_g1, const float* __restrict__ b_g1,
    const u16* __restrict__ a1, u16* __restrict__ a2, int N)
{
    __shared__ float geom_s[16 * KNN * 4];
    __shared__ int idx_s[16 * KNN];
    const int t = threadIdx.x;
    const int base = blockIdx.x * 16;

    {
        size_t off = (size_t)base * 64 + t * 4;
        size_t mx = (size_t)N * 64 - 4;
        if (off > mx) off = mx;
        *(float4*)&geom_s[t * 4] = *(const float4*)(geom + off);
        idx_s[t] = idx[min(base * KNN + t, N * KNN - 1)];
    }
    __syncthreads();

    const int pt = t >> 4, s = t & 15;
    const int n = base + pt;

    float wr[4][4], bb[4];
    #pragma unroll
    for (int r = 0; r < 4; ++r)
        #pragma unroll
        for (int j = 0; j < 4; ++j)
            wr[r][j] = w_g1[r * 64 + s * 4 + j];
    #pragma unroll
    for (int j = 0; j < 4; ++j) bb[j] = b_g1[s * 4 + j];

    float accM[4] = {0.f, 0.f, 0.f, 0.f};
    const float4* g4 = (const float4*)&geom_s[pt * 64];
    #pragma unroll
    for (int k = 0; k < KNN; ++k) {
        float4 g = g4[k];
        #pragma unroll
        for (int j = 0; j < 4; ++j)
            accM[j] += leaky(g.x * wr[0][j] + g.y * wr[1][j] + g.z * wr[2][j] + g.w * wr[3][j] + bb[j]);
    }

    float accG[4] = {0.f, 0.f, 0.f, 0.f};
    u16x4 v[KNN];
    #pragma unroll
    for (int k = 0; k < KNN; ++k)
        v[k] = *(const u16x4*)(a1 + (size_t)idx_s[pt * KNN + k] * 64 + s * 4);
    #pragma unroll
    for (int k = 0; k < KNN; ++k)
        #pragma unroll
        for (int j = 0; j < 4; ++j) accG[j] += bu2f(v[k][j]);

    if (n < N) {
        u16x4 pm, pg;
        #pragma unroll
        for (int j = 0; j < 4; ++j) {
            pm[j] = f2bu(accM[j] * 0.0625f);
            pg[j] = f2bu(accG[j] * 0.0625f);
        }
        *(u16x4*)(a2 + (size_t)n * 128 + s * 4) = pm;
        *(u16x4*)(a2 + (size_t)n * 128 + 64 + s * 4) = pg;
    }
}

// ---------------------------------------------------------------------------
// Gather3: a3h[n,0:128] = mean_k a2[idx[n,k],:]. LDS-light, high occupancy.
__global__ __launch_bounds__(256) void k_gather3(
    const int* __restrict__ idx, const u16* __restrict__ a2,
    u16* __restrict__ a3h, int N)
{
    __shared__ int idx_s[16 * KNN];
    const int t = threadIdx.x;
    const int base = blockIdx.x * 16;
    idx_s[t] = idx[min(base * KNN + t, N * KNN - 1)];
    __syncthreads();

    const int pt = t >> 4, s = t & 15;
    const int n = base + pt;

    u16x8 v[KNN];
    #pragma unroll
    for (int k = 0; k < KNN; ++k)
        v[k] = *(const u16x8*)(a2 + (size_t)idx_s[pt * KNN + k] * 128 + s * 8);

    float acc[8] = {0.f, 0.f, 0.f, 0.f, 0.f, 0.f, 0.f, 0.f};
    #pragma unroll
    for (int k = 0; k < KNN; ++k)
        #pragma unroll
        for (int j = 0; j < 8; ++j) acc[j] += bu2f(v[k][j]);

    u16x8 p;
    #pragma unroll
    for (int j = 0; j < 8; ++j) p[j] = f2bu(acc[j] * 0.0625f);
    if (n < N) *(u16x8*)(a3h + (size_t)n * 128 + s * 8) = p;
}

// ---------------------------------------------------------------------------
// MLP3: a3m[n,0:128] = mean_k leaky(geom[n,k,:] @ w_g2 + b_g2). LDS-light:
// 16 pts/block; thread (pt=t>>4, s=t&15) owns 8 cols, weights in 40 regs,
// only 16 geom LDS reads per thread (vs 512 in the fused R6 version).
// Runs AFTER k_gather3 so a3m can overlay dead a2.
__global__ __launch_bounds__(256) void k_mlp3(
    const float* __restrict__ geom, const float* __restrict__ w_g2,
    const float* __restrict__ b_g2, u16* __restrict__ a3m, int N)
{
    __shared__ float geom_s[16 * 64];  // 4 KB
    const int t = threadIdx.x;
    const int base = blockIdx.x * 16;
    {
        size_t off = (size_t)base * 64 + t * 4;
        size_t mx = (size_t)N * 64 - 4;
        if (off > mx) off = mx;
        *(float4*)&geom_s[t * 4] = *(const float4*)(geom + off);
    }
    __syncthreads();

    const int pt = t >> 4, s = t & 15;
    const int n = base + pt;

    float w0[8], w1[8], w2[8], w3[8], bb[8];
    #pragma unroll
    for (int j = 0; j < 8; ++j) {
        w0[j] = w_g2[s * 8 + j];
        w1[j] = w_g2[128 + s * 8 + j];
        w2[j] = w_g2[256 + s * 8 + j];
        w3[j] = w_g2[384 + s * 8 + j];
        bb[j] = b_g2[s * 8 + j];
    }

    float acc[8] = {0.f, 0.f, 0.f, 0.f, 0.f, 0.f, 0.f, 0.f};
    const float4* g4 = (const float4*)&geom_s[pt * 64];
    #pragma unroll
    for (int k = 0; k < KNN; ++k) {
        float4 g = g4[k];
        #pragma unroll
        for (int j = 0; j < 8; ++j)
            acc[j] += leaky(g.x * w0[j] + g.y * w1[j] + g.z * w2[j] + g.w * w3[j] + bb[j]);
    }

    if (n < N) {
        u16x8 p;
        #pragma unroll
        for (int j = 0; j < 8; ++j) p[j] = f2bu(acc[j] * 0.0625f);
        *(u16x8*)(a3m + (size_t)n * 128 + s * 8) = p;
    }
}

// ---------------------------------------------------------------------------
// GEMM3 (pure): A cols 0..127 from a3m, 128..255 from a3h (both bf16 in ws).
// K-loop identical to gemm1 (B_s staged). LDS 54272 B -> 3 blocks/CU.
// Epilogue: out = leaky(acc + b_fin) + resid (RMW on d_out).
__global__ __launch_bounds__(256, 3) void k_gemm3(
    const u16* __restrict__ a3m, const u16* __restrict__ a3h,
    const u16* __restrict__ wT3, const float* __restrict__ b_fin,
    float* __restrict__ out, int N)
{
    __shared__ u16 A_s[64 * APAD];   // 33792 B
    __shared__ u16 B_s[256 * BPAD];  // 20480 B
    const int t = threadIdx.x;
    const int base = blockIdx.x * 64;

    // stage A: thread t -> row t>>2, quarter q = t&3 (64 u16 each)
    {
        const int row = t >> 2, q = t & 3;
        const int grow = min(base + row, N - 1);
        const u16* src = (q < 2) ? (a3m + (size_t)grow * 128 + q * 64)
                                 : (a3h + (size_t)grow * 128 + (q - 2) * 64);
        u16* dst = &A_s[row * APAD + q * 64];
        #pragma unroll
        for (int j = 0; j < 8; ++j)
            *(u16x8*)(dst + j * 8) = *(const u16x8*)(src + j * 8);
    }

    f32x4 acc[4][4];
    #pragma unroll
    for (int i = 0; i < 4; ++i)
        #pragma unroll
        for (int j = 0; j < 4; ++j)
            acc[i][j] = (f32x4){0.f, 0.f, 0.f, 0.f};

    const int w = t >> 6, lane = t & 63;
    const int llow = lane & 15, lhi = lane >> 4;

    for (int ks = 0; ks < 8; ++ks) {
        u16x8 breg[4];
        #pragma unroll
        for (int kg = 0; kg < 4; ++kg)
            breg[kg] = *(const u16x8*)(wT3 + t * 256 + ks * 32 + kg * 8);
        __syncthreads();  // A_s writes done (ks=0) / prev frag reads done
        #pragma unroll
        for (int kg = 0; kg < 4; ++kg)
            *(u16x8*)(&B_s[t * BPAD + kg * 8]) = breg[kg];
        __syncthreads();

        s16x8 afrag[4];
        #pragma unroll
        for (int rt = 0; rt < 4; ++rt)
            afrag[rt] = *(const s16x8*)(&A_s[(rt * 16 + llow) * APAD + ks * 32 + lhi * 8]);
        #pragma unroll
        for (int ci = 0; ci < 4; ++ci) {
            const int ct = w * 4 + ci;
            s16x8 bfrag = *(const s16x8*)(&B_s[(ct * 16 + llow) * BPAD + lhi * 8]);
            #pragma unroll
            for (int rt = 0; rt < 4; ++rt)
                acc[rt][ci] = __builtin_amdgcn_mfma_f32_16x16x32_bf16(
                    afrag[rt], bfrag, acc[rt][ci], 0, 0, 0);
        }
    }

    #pragma unroll
    for (int ci = 0; ci < 4; ++ci) {
        const int ct = w * 4 + ci;
        const int col = ct * 16 + llow;
        const float bias = b_fin[col];
        #pragma unroll
        for (int rt = 0; rt < 4; ++rt)
            #pragma unroll
            for (int r = 0; r < 4; ++r) {
                int row = base + rt * 16 + lhi * 4 + r;
                if (row < N) {
                    size_t o = (size_t)row * DIM + col;
                    out[o] = leaky(acc[rt][ci][r] + bias) + out[o];
                }
            }
    }
}

// ---------------------------------------------------------------------------
extern "C" void kernel_launch(void* const* d_in, const int* in_sizes, int n_in,
                              void* d_out, int out_size, void* d_ws, size_t ws_size,
                              hipStream_t stream) {
    const float* in    = (const float*)d_in[0];
    const float* geom  = (const float*)d_in[1];
    const int*   idx   = (const int*)d_in[2];
    const float* w_res = (const float*)d_in[3];
    const float* b_res = (const float*)d_in[4];
    const float* w_init= (const float*)d_in[5];
    const float* b_init= (const float*)d_in[6];
    const float* w_g1  = (const float*)d_in[7];
    const float* b_g1  = (const float*)d_in[8];
    const float* w_g2  = (const float*)d_in[9];
    const float* b_g2  = (const float*)d_in[10];
    const float* w_fin = (const float*)d_in[11];
    const float* b_fin = (const float*)d_in[12];
    float* out = (float*)d_out;

    const int N = in_sizes[0] / DIM;  // 50000

    // ws (25.9 MB):
    //  region0 [N*128 u16]: a1 (first N*64, lifetime gemm1->lfa1) then a3h
    //  region1 [N*128 u16]: a2 (lifetime lfa1->gather3) then a3m (mlp3->gemm3)
    //  wT1 320*256 u16 | wT3 256*256 u16
    char* ws = (char*)d_ws;
    u16* a1  = (u16*)ws;
    u16* a3h = (u16*)ws;
    u16* a2  = (u16*)(ws + (size_t)N * 128 * 2);
    u16* a3m = a2;
    u16* wT1 = (u16*)(ws + (size_t)N * 256 * 2);
    u16* wT3 = wT1 + 320 * 256;

    k_prep<<<576, 256, 0, stream>>>(w_res, w_init, w_fin, wT1, wT3);
    k_gemm1<<<(N + 63) / 64, 256, 0, stream>>>(in, wT1, b_res, b_init, out, a1, N);
    k_lfa1<<<(N + 15) / 16, 256, 0, stream>>>(geom, idx, w_g1, b_g1, a1, a2, N);
    k_gather3<<<(N + 15) / 16, 256, 0, stream>>>(idx, a2, a3h, N);
    k_mlp3<<<(N + 15) / 16, 256, 0, stream>>>(geom, w_g2, b_g2, a3m, N);
    k_gemm3<<<(N + 63) / 64, 256, 0, stream>>>(a3m, a3h, wT3, b_fin, out, N);
}